// Round 1
// baseline (10653.757 us; speedup 1.0000x reference)
//
#include <hip/hip_runtime.h>
#include <hip/hip_bf16.h>

#define NN   50000
#define EE   800000
#define FIN  32
#define HH   128
#define LL   4
#define NOUT 20

__device__ __forceinline__ float silu_f(float v){ return v / (1.f + __expf(-v)); }
__device__ __forceinline__ float sigm_f(float v){ return 1.f / (1.f + __expf(-v)); }

__device__ __forceinline__ float wave_sum(float r){
  r += __shfl_xor(r, 1);  r += __shfl_xor(r, 2);  r += __shfl_xor(r, 4);
  r += __shfl_xor(r, 8);  r += __shfl_xor(r, 16); r += __shfl_xor(r, 32);
  return r;
}

// acc[i] += buf[eo*32+i][k] * W[k][c] over k = 0..127 (W row-major [*, 128])
__device__ __forceinline__ void gemm_accum(const float (*buf)[132], const float* __restrict__ W,
                                           int c, int eo, float acc[32])
{
  for (int k0 = 0; k0 < HH; k0 += 4) {
    const float w0 = W[(k0+0)*HH + c];
    const float w1 = W[(k0+1)*HH + c];
    const float w2 = W[(k0+2)*HH + c];
    const float w3 = W[(k0+3)*HH + c];
    #pragma unroll
    for (int i = 0; i < 32; i++) {
      const float4 a = *(const float4*)&buf[eo*32+i][k0];
      acc[i] = fmaf(a.x, w0, fmaf(a.y, w1, fmaf(a.z, w2, fmaf(a.w, w3, acc[i]))));
    }
  }
}

// ---------------- input embedding + x copy ----------------
__global__ __launch_bounds__(256)
void k_embed(const float* __restrict__ hin, const float* __restrict__ xin,
             const float* __restrict__ W, const float* __restrict__ b,
             float* __restrict__ hout, float* __restrict__ xout)
{
  __shared__ float wl[FIN*HH];
  const int tid = threadIdx.x;
  for (int j = tid; j < FIN*HH; j += 256) wl[j] = W[j];
  __syncthreads();
  const int c  = tid & (HH-1);
  const int no = tid >> 7;
  const int v  = blockIdx.x * 2 + no;
  if (v < NN) {
    const float* hr = hin + (size_t)v * FIN;
    float acc = b[c];
    #pragma unroll
    for (int k = 0; k < FIN; k++) acc = fmaf(hr[k], wl[k*HH + c], acc);
    hout[(size_t)v*HH + c] = acc;
    if (c < 3) xout[v*3 + c] = xin[v*3 + c];
  }
}

// ---------------- in-degree count (cnt is layer-invariant) ----------------
__global__ __launch_bounds__(256)
void k_count(const int* __restrict__ row, float* __restrict__ cnt)
{
  const int e = blockIdx.x * 256 + threadIdx.x;
  if (e < EE) atomicAdd(&cnt[row[e]], 1.f);
}

// ---------------- fused edge pipeline for one layer ----------------
__global__ __launch_bounds__(256, 2)
void k_edge(const float* __restrict__ hbuf, const float* __restrict__ xbuf,
            const int* __restrict__ row, const int* __restrict__ col,
            const float* __restrict__ W1, const float* __restrict__ b1,
            const float* __restrict__ W2, const float* __restrict__ b2,
            const float* __restrict__ attw, const float* __restrict__ attb,
            const float* __restrict__ cw1, const float* __restrict__ cb1,
            const float* __restrict__ cw2,
            float* __restrict__ aggm, float* __restrict__ aggx)
{
  __shared__ float bufA[64][132];
  __shared__ float bufB[64][132];
  __shared__ float red[4][32];
  __shared__ int   rowb[64];
  __shared__ int   colb[64];
  __shared__ float diffb[64][3];
  __shared__ float radb[64];

  const int tid = threadIdx.x;
  const int c   = tid & (HH-1);
  const int eo  = tid >> 7;   // 0/1: which half of the edge tile
  const int wv  = tid >> 6;   // wave id 0..3
  const int eb  = blockIdx.x * 64;

  if (tid < 64) {
    const int r  = row[eb + tid];
    const int cl = col[eb + tid];
    rowb[tid] = r; colb[tid] = cl;
    const float dx = xbuf[r*3+0] - xbuf[cl*3+0];
    const float dy = xbuf[r*3+1] - xbuf[cl*3+1];
    const float dz = xbuf[r*3+2] - xbuf[cl*3+2];
    diffb[tid][0] = dx; diffb[tid][1] = dy; diffb[tid][2] = dz;
    radb[tid] = dx*dx + dy*dy + dz*dz;
  }
  __syncthreads();

  // stage h[row] tile
  #pragma unroll
  for (int i = 0; i < 32; i++) {
    const int e = eo*32 + i;
    bufA[e][c] = hbuf[(size_t)rowb[e]*HH + c];
  }
  __syncthreads();

  float acc[32];
  #pragma unroll
  for (int i = 0; i < 32; i++) acc[i] = 0.f;

  // GEMM1 part A: h[row] @ W1[0:128]
  gemm_accum(bufA, W1, c, eo, acc);
  __syncthreads();

  // restage with h[col]
  #pragma unroll
  for (int i = 0; i < 32; i++) {
    const int e = eo*32 + i;
    bufA[e][c] = hbuf[(size_t)colb[e]*HH + c];
  }
  __syncthreads();

  // GEMM1 part B: h[col] @ W1[128:256]
  gemm_accum(bufA, W1 + HH*HH, c, eo, acc);

  // radial term: row 256
  {
    const float wr = W1[(2*HH)*HH + c];
    #pragma unroll
    for (int i = 0; i < 32; i++) acc[i] = fmaf(radb[eo*32+i], wr, acc[i]);
  }
  // bias + silu -> bufB (m1)
  {
    const float bb = b1[c];
    #pragma unroll
    for (int i = 0; i < 32; i++) bufB[eo*32+i][c] = silu_f(acc[i] + bb);
  }
  __syncthreads();

  // GEMM2: m1 @ W2
  #pragma unroll
  for (int i = 0; i < 32; i++) acc[i] = 0.f;
  gemm_accum(bufB, W2, c, eo, acc);
  {
    const float bb = b2[c];
    #pragma unroll
    for (int i = 0; i < 32; i++) acc[i] = silu_f(acc[i] + bb);  // m2
  }

  // attention gate: att = sigmoid(m2 . attw + attb)
  {
    const float aw = attw[c];
    #pragma unroll
    for (int i = 0; i < 32; i++) {
      float r = wave_sum(acc[i] * aw);
      if ((tid & 63) == 0) red[wv][i] = r;
    }
  }
  __syncthreads();
  {
    const float ab = attb[0];
    #pragma unroll
    for (int i = 0; i < 32; i++) {
      const float att = sigm_f(red[eo*2][i] + red[eo*2+1][i] + ab);
      acc[i] *= att;                 // gated m (kept for agg_m atomics)
      bufA[eo*32+i][c] = acc[i];     // stage m for coord GEMM
    }
  }
  __syncthreads();

  // GEMM3: coord layer1, then scalar coord weight
  float acc3[32];
  #pragma unroll
  for (int i = 0; i < 32; i++) acc3[i] = 0.f;
  gemm_accum(bufA, cw1, c, eo, acc3);
  {
    const float bb = cb1[c];
    const float c2 = cw2[c];
    #pragma unroll
    for (int i = 0; i < 32; i++) {
      float r = wave_sum(silu_f(acc3[i] + bb) * c2);
      if ((tid & 63) == 0) red[wv][i] = r;
    }
  }
  __syncthreads();

  // coordinate aggregation (3 atomics/edge)
  if (tid < 64) {
    const int e = tid, i = e & 31, g2 = e >> 5;
    const float cw = red[g2*2][i] + red[g2*2+1][i];
    const int r = rowb[e];
    atomicAdd(&aggx[r*3+0], diffb[e][0]*cw);
    atomicAdd(&aggx[r*3+1], diffb[e][1]*cw);
    atomicAdd(&aggx[r*3+2], diffb[e][2]*cw);
  }

  // message aggregation (128 atomics/edge)
  #pragma unroll
  for (int i = 0; i < 32; i++) {
    atomicAdd(&aggm[(size_t)rowb[eo*32+i]*HH + c], acc[i]);
  }
}

// ---------------- fused node update for one layer ----------------
__global__ __launch_bounds__(256, 2)
void k_node(float* __restrict__ hbuf, float* __restrict__ xbuf,
            const float* __restrict__ aggm, const float* __restrict__ aggx,
            const float* __restrict__ cnt,
            const float* __restrict__ W1, const float* __restrict__ b1,
            const float* __restrict__ W2, const float* __restrict__ b2)
{
  __shared__ float bufA[64][132];
  __shared__ float bufB[64][132];
  const int tid = threadIdx.x;
  const int c   = tid & (HH-1);
  const int no  = tid >> 7;
  const int nb  = blockIdx.x * 64;

  #pragma unroll
  for (int i = 0; i < 32; i++) {
    const int v = nb + no*32 + i;
    bufA[no*32+i][c] = (v < NN) ? hbuf[(size_t)v*HH + c] : 0.f;
  }
  __syncthreads();

  float acc[32];
  #pragma unroll
  for (int i = 0; i < 32; i++) acc[i] = 0.f;
  gemm_accum(bufA, W1, c, no, acc);          // h part
  __syncthreads();

  #pragma unroll
  for (int i = 0; i < 32; i++) {
    const int v = nb + no*32 + i;
    bufA[no*32+i][c] = (v < NN) ? aggm[(size_t)v*HH + c] : 0.f;
  }
  __syncthreads();
  gemm_accum(bufA, W1 + HH*HH, c, no, acc);  // agg_m part
  {
    const float bb = b1[c];
    #pragma unroll
    for (int i = 0; i < 32; i++) bufB[no*32+i][c] = silu_f(acc[i] + bb);
  }
  __syncthreads();

  #pragma unroll
  for (int i = 0; i < 32; i++) acc[i] = 0.f;
  gemm_accum(bufB, W2, c, no, acc);
  {
    const float bb = b2[c];
    #pragma unroll
    for (int i = 0; i < 32; i++) {
      const int v = nb + no*32 + i;
      if (v < NN) hbuf[(size_t)v*HH + c] += acc[i] + bb;   // residual
    }
  }

  // coordinate mean update
  if (tid < 64) {
    const int v = nb + tid;
    if (v < NN) {
      const float ct = fmaxf(cnt[v], 1.f);
      xbuf[v*3+0] += aggx[v*3+0] / ct;
      xbuf[v*3+1] += aggx[v*3+1] / ct;
      xbuf[v*3+2] += aggx[v*3+2] / ct;
    }
  }
}

// ---------------- mean pool (sum; divide later) ----------------
__global__ __launch_bounds__(128)
void k_pool(const float* __restrict__ h, float* __restrict__ g)
{
  const int c  = threadIdx.x;          // 128
  const int v0 = blockIdx.x * 100;     // 500 blocks * 100 rows
  float s = 0.f;
  for (int v = v0; v < v0 + 100; ++v) s += h[(size_t)v*HH + c];
  atomicAdd(&g[c], s);
}

// ---------------- out-embed (folded through mean) + head MLP ----------------
__global__ __launch_bounds__(128)
void k_head(const float* __restrict__ g,
            const float* __restrict__ eow, const float* __restrict__ eob,
            const float* __restrict__ hw1, const float* __restrict__ hb1,
            const float* __restrict__ hw2, const float* __restrict__ hb2,
            float* __restrict__ out)
{
  __shared__ float gm[HH], ho[HH], t1[HH];
  const int c = threadIdx.x;
  gm[c] = g[c] * (1.f / (float)NN);
  __syncthreads();
  float a = eob[c];
  for (int k = 0; k < HH; k++) a = fmaf(gm[k], eow[k*HH + c], a);
  ho[c] = a;
  __syncthreads();
  float t = hb1[c];
  for (int k = 0; k < HH; k++) t = fmaf(ho[k], hw1[k*HH + c], t);
  t1[c] = fmaxf(t, 0.f);
  __syncthreads();
  if (c < NOUT) {
    float o = hb2[c];
    for (int k = 0; k < HH; k++) o = fmaf(t1[k], hw2[k*NOUT + c], o);
    out[c] = o;
  }
}

extern "C" void kernel_launch(void* const* d_in, const int* in_sizes, int n_in,
                              void* d_out, int out_size, void* d_ws, size_t ws_size,
                              hipStream_t stream)
{
  const float* in_h  = (const float*)d_in[0];
  const float* in_x  = (const float*)d_in[1];
  const int*   edges = (const int*)  d_in[2];
  const float* eiw   = (const float*)d_in[3];
  const float* eib   = (const float*)d_in[4];
  const float* eow   = (const float*)d_in[5];
  const float* eob   = (const float*)d_in[6];
  const float* ew1   = (const float*)d_in[7];
  const float* eb1   = (const float*)d_in[8];
  const float* ew2   = (const float*)d_in[9];
  const float* eb2   = (const float*)d_in[10];
  const float* attw  = (const float*)d_in[11];
  const float* attb  = (const float*)d_in[12];
  const float* cw1   = (const float*)d_in[13];
  const float* cb1   = (const float*)d_in[14];
  const float* cw2   = (const float*)d_in[15];
  const float* nw1   = (const float*)d_in[16];
  const float* nb1   = (const float*)d_in[17];
  const float* nw2   = (const float*)d_in[18];
  const float* nb2   = (const float*)d_in[19];
  const float* hw1   = (const float*)d_in[20];
  const float* hb1   = (const float*)d_in[21];
  const float* hw2   = (const float*)d_in[22];
  const float* hb2   = (const float*)d_in[23];

  const int* row = edges;
  const int* col = edges + EE;

  float* ws   = (float*)d_ws;
  float* h    = ws;                          // NN*HH
  float* x    = h    + (size_t)NN*HH;        // NN*3
  float* aggm = x    + (size_t)NN*3;         // NN*HH
  float* aggx = aggm + (size_t)NN*HH;        // NN*3
  float* cnt  = aggx + (size_t)NN*3;         // NN
  float* g    = cnt  + (size_t)NN;           // HH

  k_embed<<<NN/2, 256, 0, stream>>>(in_h, in_x, eiw, eib, h, x);

  hipMemsetAsync(cnt, 0, (size_t)NN*sizeof(float), stream);
  k_count<<<EE/256, 256, 0, stream>>>(row, cnt);

  for (int l = 0; l < LL; l++) {
    hipMemsetAsync(aggm, 0, (size_t)NN*HH*sizeof(float), stream);
    hipMemsetAsync(aggx, 0, (size_t)NN*3*sizeof(float), stream);
    k_edge<<<EE/64, 256, 0, stream>>>(h, x, row, col,
        ew1 + (size_t)l*(2*HH+1)*HH, eb1 + l*HH,
        ew2 + (size_t)l*HH*HH,       eb2 + l*HH,
        attw + l*HH, attb + l,
        cw1 + (size_t)l*HH*HH, cb1 + l*HH, cw2 + l*HH,
        aggm, aggx);
    k_node<<<(NN + 63)/64, 256, 0, stream>>>(h, x, aggm, aggx, cnt,
        nw1 + (size_t)l*(2*HH)*HH, nb1 + l*HH,
        nw2 + (size_t)l*HH*HH,     nb2 + l*HH);
  }

  hipMemsetAsync(g, 0, HH*sizeof(float), stream);
  k_pool<<<500, 128, 0, stream>>>(h, g);
  k_head<<<1, 128, 0, stream>>>(g, eow, eob, hw1, hb1, hw2, hb2, (float*)d_out);
}

// Round 2
// 8080.665 us; speedup vs baseline: 1.3184x; 1.3184x over previous
//
#include <hip/hip_runtime.h>
#include <hip/hip_bf16.h>

#define NN   50000
#define EE   800000
#define FIN  32
#define HH   128
#define LL   4
#define NOUT 20

__device__ __forceinline__ float silu_f(float v){ return v / (1.f + __expf(-v)); }
__device__ __forceinline__ float sigm_f(float v){ return 1.f / (1.f + __expf(-v)); }

// ---------------------------------------------------------------------------
// Register-tiled edge GEMM helpers.
// Activation LDS layout (swizzled, stride 128, conflict-free for the access
// patterns below): element (e,k) stored at  e*128 + (((k>>2)^(e&7))<<2) + (k&3)
// Thread mapping: eg = tid&7, cg = tid>>3, c0 = cg*4, edges e = eg + 8*i.
// ---------------------------------------------------------------------------

#define FMA16(a, w0, w1, w2, w3, r) \
  r.x = fmaf(a.x, w0.x, r.x); r.y = fmaf(a.x, w0.y, r.y); \
  r.z = fmaf(a.x, w0.z, r.z); r.w = fmaf(a.x, w0.w, r.w); \
  r.x = fmaf(a.y, w1.x, r.x); r.y = fmaf(a.y, w1.y, r.y); \
  r.z = fmaf(a.y, w1.z, r.z); r.w = fmaf(a.y, w1.w, r.w); \
  r.x = fmaf(a.z, w2.x, r.x); r.y = fmaf(a.z, w2.y, r.y); \
  r.z = fmaf(a.z, w2.z, r.z); r.w = fmaf(a.z, w2.w, r.w); \
  r.x = fmaf(a.w, w3.x, r.x); r.y = fmaf(a.w, w3.y, r.y); \
  r.z = fmaf(a.w, w3.z, r.z); r.w = fmaf(a.w, w3.w, r.w);

__device__ __forceinline__ void gemm_rt(const float* Abuf, const float* __restrict__ W,
                                        int eg, int c0, float4 acc[8])
{
  #pragma unroll 1
  for (int k0 = 0; k0 < HH; k0 += 4) {
    const int slot = (((k0 >> 2) ^ eg) << 2);
    float4 a[8];
    #pragma unroll
    for (int i = 0; i < 8; i++)
      a[i] = *(const float4*)&Abuf[(eg + 8*i)*HH + slot];
    const float4 w0 = *(const float4*)&W[(size_t)(k0+0)*HH + c0];
    const float4 w1 = *(const float4*)&W[(size_t)(k0+1)*HH + c0];
    const float4 w2 = *(const float4*)&W[(size_t)(k0+2)*HH + c0];
    const float4 w3 = *(const float4*)&W[(size_t)(k0+3)*HH + c0];
    #pragma unroll
    for (int i = 0; i < 8; i++) { FMA16(a[i], w0, w1, w2, w3, acc[i]); }
  }
}

// ---------------- input embedding + x copy ----------------
__global__ __launch_bounds__(256)
void k_embed(const float* __restrict__ hin, const float* __restrict__ xin,
             const float* __restrict__ W, const float* __restrict__ b,
             float* __restrict__ hout, float* __restrict__ xout)
{
  __shared__ float wl[FIN*HH];
  const int tid = threadIdx.x;
  for (int j = tid; j < FIN*HH; j += 256) wl[j] = W[j];
  __syncthreads();
  const int c  = tid & (HH-1);
  const int no = tid >> 7;
  const int v  = blockIdx.x * 2 + no;
  if (v < NN) {
    const float* hr = hin + (size_t)v * FIN;
    float acc = b[c];
    #pragma unroll
    for (int k = 0; k < FIN; k++) acc = fmaf(hr[k], wl[k*HH + c], acc);
    hout[(size_t)v*HH + c] = acc;
    if (c < 3) xout[v*3 + c] = xin[v*3 + c];
  }
}

// ---------------- in-degree count (layer-invariant) ----------------
__global__ __launch_bounds__(256)
void k_count(const int* __restrict__ row, float* __restrict__ cnt)
{
  const int e = blockIdx.x * 256 + threadIdx.x;
  if (e < EE) atomicAdd(&cnt[row[e]], 1.f);
}

// ---------------- fused edge pipeline for one layer (register-tiled) -------
__global__ __launch_bounds__(256, 2)
void k_edge(const float* __restrict__ hbuf, const float* __restrict__ xbuf,
            const int* __restrict__ row, const int* __restrict__ col,
            const float* __restrict__ W1, const float* __restrict__ b1,
            const float* __restrict__ W2, const float* __restrict__ b2,
            const float* __restrict__ attw, const float* __restrict__ attb,
            const float* __restrict__ cw1, const float* __restrict__ cb1,
            const float* __restrict__ cw2,
            float* __restrict__ aggm, float* __restrict__ aggx)
{
  __shared__ float A[64*HH];
  __shared__ float B[64*HH];
  __shared__ float red[4][64];
  __shared__ float scal[64];
  __shared__ int   rowb[64];
  __shared__ int   colb[64];
  __shared__ float diffb[64][3];
  __shared__ float radb[64];

  const int tid  = threadIdx.x;
  const int eg   = tid & 7;
  const int cg   = tid >> 3;       // 0..31
  const int c0   = cg * 4;
  const int lane = tid & 63;
  const int wv   = tid >> 6;
  const int eb   = blockIdx.x * 64;

  if (tid < 64) {
    const int r  = row[eb + tid];
    const int cl = col[eb + tid];
    rowb[tid] = r; colb[tid] = cl;
    const float dx = xbuf[r*3+0] - xbuf[cl*3+0];
    const float dy = xbuf[r*3+1] - xbuf[cl*3+1];
    const float dz = xbuf[r*3+2] - xbuf[cl*3+2];
    diffb[tid][0] = dx; diffb[tid][1] = dy; diffb[tid][2] = dz;
    radb[tid] = dx*dx + dy*dy + dz*dz;
  }
  __syncthreads();

  // gather h[row] -> A, h[col] -> B (coalesced 512B per 32-lane group)
  {
    const int l32 = tid & 31;
    const int hgr = tid >> 5;          // 0..7
    const int c4  = l32 * 4;
    const int slotg = (((c4 >> 2) ^ (hgr & 7)) << 2);
    #pragma unroll
    for (int j = 0; j < 8; j++) {
      const int e = hgr + 8*j;         // e&7 == hgr&7
      const float4 v = *(const float4*)&hbuf[(size_t)rowb[e]*HH + c4];
      *(float4*)&A[e*HH + slotg] = v;
      const float4 u = *(const float4*)&hbuf[(size_t)colb[e]*HH + c4];
      *(float4*)&B[e*HH + slotg] = u;
    }
  }
  __syncthreads();

  // ---- GEMM1: [h_row | h_col | radial] @ W1 + b1, silu ----
  float4 acc[8];
  {
    const float4 wr = *(const float4*)&W1[(size_t)(2*HH)*HH + c0];
    const float4 bb = *(const float4*)&b1[c0];
    #pragma unroll
    for (int i = 0; i < 8; i++) {
      const float rr = radb[eg + 8*i];
      acc[i].x = fmaf(rr, wr.x, bb.x);
      acc[i].y = fmaf(rr, wr.y, bb.y);
      acc[i].z = fmaf(rr, wr.z, bb.z);
      acc[i].w = fmaf(rr, wr.w, bb.w);
    }
  }
  gemm_rt(A, W1,          eg, c0, acc);
  gemm_rt(B, W1 + HH*HH,  eg, c0, acc);
  #pragma unroll
  for (int i = 0; i < 8; i++) {
    acc[i].x = silu_f(acc[i].x); acc[i].y = silu_f(acc[i].y);
    acc[i].z = silu_f(acc[i].z); acc[i].w = silu_f(acc[i].w);
  }
  __syncthreads();   // all reads of A,B done
  {
    const int slotw = (((c0 >> 2) ^ eg) << 2);
    #pragma unroll
    for (int i = 0; i < 8; i++) *(float4*)&A[(eg + 8*i)*HH + slotw] = acc[i];
  }
  __syncthreads();

  // ---- GEMM2: m1 @ W2 + b2, silu -> m2 ----
  float4 m2[8];
  {
    const float4 bb = *(const float4*)&b2[c0];
    #pragma unroll
    for (int i = 0; i < 8; i++) m2[i] = bb;
  }
  gemm_rt(A, W2, eg, c0, m2);
  #pragma unroll
  for (int i = 0; i < 8; i++) {
    m2[i].x = silu_f(m2[i].x); m2[i].y = silu_f(m2[i].y);
    m2[i].z = silu_f(m2[i].z); m2[i].w = silu_f(m2[i].w);
  }

  // ---- attention gate: sigmoid(m2 . attw + attb) per edge ----
  {
    const float4 aw = *(const float4*)&attw[c0];
    #pragma unroll
    for (int i = 0; i < 8; i++) {
      float p = m2[i].x*aw.x;
      p = fmaf(m2[i].y, aw.y, p);
      p = fmaf(m2[i].z, aw.z, p);
      p = fmaf(m2[i].w, aw.w, p);
      p += __shfl_xor(p, 8); p += __shfl_xor(p, 16); p += __shfl_xor(p, 32);
      if ((lane >> 3) == 0) red[wv][eg + 8*i] = p;
    }
  }
  __syncthreads();
  if (tid < 64)
    scal[tid] = sigm_f(red[0][tid] + red[1][tid] + red[2][tid] + red[3][tid] + attb[0]);
  __syncthreads();

  // ---- gate m, stash to B for coord GEMM, fire aggm atomics early ----
  {
    const int slotw = (((c0 >> 2) ^ eg) << 2);
    #pragma unroll
    for (int i = 0; i < 8; i++) {
      const int e = eg + 8*i;
      const float at = scal[e];
      float4 m = m2[i];
      m.x *= at; m.y *= at; m.z *= at; m.w *= at;
      *(float4*)&B[e*HH + slotw] = m;
      float* dst = &aggm[(size_t)rowb[e]*HH + c0];
      atomicAdd(dst+0, m.x); atomicAdd(dst+1, m.y);
      atomicAdd(dst+2, m.z); atomicAdd(dst+3, m.w);
    }
  }
  __syncthreads();

  // ---- GEMM3: coord MLP layer1 (silu) then dot with cw2 ----
  float4 a3[8];
  {
    const float4 bb = *(const float4*)&cb1[c0];
    #pragma unroll
    for (int i = 0; i < 8; i++) a3[i] = bb;
  }
  gemm_rt(B, cw1, eg, c0, a3);
  {
    const float4 c2 = *(const float4*)&cw2[c0];
    #pragma unroll
    for (int i = 0; i < 8; i++) {
      float p = silu_f(a3[i].x)*c2.x;
      p = fmaf(silu_f(a3[i].y), c2.y, p);
      p = fmaf(silu_f(a3[i].z), c2.z, p);
      p = fmaf(silu_f(a3[i].w), c2.w, p);
      p += __shfl_xor(p, 8); p += __shfl_xor(p, 16); p += __shfl_xor(p, 32);
      if ((lane >> 3) == 0) red[wv][eg + 8*i] = p;
    }
  }
  __syncthreads();

  // ---- coordinate aggregation (3 atomics/edge) ----
  if (tid < 64) {
    const float cw = red[0][tid] + red[1][tid] + red[2][tid] + red[3][tid];
    const int r = rowb[tid];
    atomicAdd(&aggx[r*3+0], diffb[tid][0]*cw);
    atomicAdd(&aggx[r*3+1], diffb[tid][1]*cw);
    atomicAdd(&aggx[r*3+2], diffb[tid][2]*cw);
  }
}

// ---------------- fused node update for one layer (unchanged) ----------------
__device__ __forceinline__ void gemm_accum(const float (*buf)[132], const float* __restrict__ W,
                                           int c, int eo, float acc[32])
{
  for (int k0 = 0; k0 < HH; k0 += 4) {
    const float w0 = W[(k0+0)*HH + c];
    const float w1 = W[(k0+1)*HH + c];
    const float w2 = W[(k0+2)*HH + c];
    const float w3 = W[(k0+3)*HH + c];
    #pragma unroll
    for (int i = 0; i < 32; i++) {
      const float4 a = *(const float4*)&buf[eo*32+i][k0];
      acc[i] = fmaf(a.x, w0, fmaf(a.y, w1, fmaf(a.z, w2, fmaf(a.w, w3, acc[i]))));
    }
  }
}

__global__ __launch_bounds__(256, 2)
void k_node(float* __restrict__ hbuf, float* __restrict__ xbuf,
            const float* __restrict__ aggm, const float* __restrict__ aggx,
            const float* __restrict__ cnt,
            const float* __restrict__ W1, const float* __restrict__ b1,
            const float* __restrict__ W2, const float* __restrict__ b2)
{
  __shared__ float bufA[64][132];
  __shared__ float bufB[64][132];
  const int tid = threadIdx.x;
  const int c   = tid & (HH-1);
  const int no  = tid >> 7;
  const int nb  = blockIdx.x * 64;

  #pragma unroll
  for (int i = 0; i < 32; i++) {
    const int v = nb + no*32 + i;
    bufA[no*32+i][c] = (v < NN) ? hbuf[(size_t)v*HH + c] : 0.f;
  }
  __syncthreads();

  float acc[32];
  #pragma unroll
  for (int i = 0; i < 32; i++) acc[i] = 0.f;
  gemm_accum(bufA, W1, c, no, acc);
  __syncthreads();

  #pragma unroll
  for (int i = 0; i < 32; i++) {
    const int v = nb + no*32 + i;
    bufA[no*32+i][c] = (v < NN) ? aggm[(size_t)v*HH + c] : 0.f;
  }
  __syncthreads();
  gemm_accum(bufA, W1 + HH*HH, c, no, acc);
  {
    const float bb = b1[c];
    #pragma unroll
    for (int i = 0; i < 32; i++) bufB[no*32+i][c] = silu_f(acc[i] + bb);
  }
  __syncthreads();

  #pragma unroll
  for (int i = 0; i < 32; i++) acc[i] = 0.f;
  gemm_accum(bufB, W2, c, no, acc);
  {
    const float bb = b2[c];
    #pragma unroll
    for (int i = 0; i < 32; i++) {
      const int v = nb + no*32 + i;
      if (v < NN) hbuf[(size_t)v*HH + c] += acc[i] + bb;
    }
  }

  if (tid < 64) {
    const int v = nb + tid;
    if (v < NN) {
      const float ct = fmaxf(cnt[v], 1.f);
      xbuf[v*3+0] += aggx[v*3+0] / ct;
      xbuf[v*3+1] += aggx[v*3+1] / ct;
      xbuf[v*3+2] += aggx[v*3+2] / ct;
    }
  }
}

// ---------------- mean pool (sum; divide later) ----------------
__global__ __launch_bounds__(128)
void k_pool(const float* __restrict__ h, float* __restrict__ g)
{
  const int c  = threadIdx.x;
  const int v0 = blockIdx.x * 100;
  float s = 0.f;
  for (int v = v0; v < v0 + 100; ++v) s += h[(size_t)v*HH + c];
  atomicAdd(&g[c], s);
}

// ---------------- out-embed (folded through mean) + head MLP ----------------
__global__ __launch_bounds__(128)
void k_head(const float* __restrict__ g,
            const float* __restrict__ eow, const float* __restrict__ eob,
            const float* __restrict__ hw1, const float* __restrict__ hb1,
            const float* __restrict__ hw2, const float* __restrict__ hb2,
            float* __restrict__ out)
{
  __shared__ float gm[HH], ho[HH], t1[HH];
  const int c = threadIdx.x;
  gm[c] = g[c] * (1.f / (float)NN);
  __syncthreads();
  float a = eob[c];
  for (int k = 0; k < HH; k++) a = fmaf(gm[k], eow[k*HH + c], a);
  ho[c] = a;
  __syncthreads();
  float t = hb1[c];
  for (int k = 0; k < HH; k++) t = fmaf(ho[k], hw1[k*HH + c], t);
  t1[c] = fmaxf(t, 0.f);
  __syncthreads();
  if (c < NOUT) {
    float o = hb2[c];
    for (int k = 0; k < HH; k++) o = fmaf(t1[k], hw2[k*NOUT + c], o);
    out[c] = o;
  }
}

extern "C" void kernel_launch(void* const* d_in, const int* in_sizes, int n_in,
                              void* d_out, int out_size, void* d_ws, size_t ws_size,
                              hipStream_t stream)
{
  const float* in_h  = (const float*)d_in[0];
  const float* in_x  = (const float*)d_in[1];
  const int*   edges = (const int*)  d_in[2];
  const float* eiw   = (const float*)d_in[3];
  const float* eib   = (const float*)d_in[4];
  const float* eow   = (const float*)d_in[5];
  const float* eob   = (const float*)d_in[6];
  const float* ew1   = (const float*)d_in[7];
  const float* eb1   = (const float*)d_in[8];
  const float* ew2   = (const float*)d_in[9];
  const float* eb2   = (const float*)d_in[10];
  const float* attw  = (const float*)d_in[11];
  const float* attb  = (const float*)d_in[12];
  const float* cw1   = (const float*)d_in[13];
  const float* cb1   = (const float*)d_in[14];
  const float* cw2   = (const float*)d_in[15];
  const float* nw1   = (const float*)d_in[16];
  const float* nb1   = (const float*)d_in[17];
  const float* nw2   = (const float*)d_in[18];
  const float* nb2   = (const float*)d_in[19];
  const float* hw1   = (const float*)d_in[20];
  const float* hb1   = (const float*)d_in[21];
  const float* hw2   = (const float*)d_in[22];
  const float* hb2   = (const float*)d_in[23];

  const int* row = edges;
  const int* col = edges + EE;

  float* ws   = (float*)d_ws;
  float* h    = ws;
  float* x    = h    + (size_t)NN*HH;
  float* aggm = x    + (size_t)NN*3;
  float* aggx = aggm + (size_t)NN*HH;
  float* cnt  = aggx + (size_t)NN*3;
  float* g    = cnt  + (size_t)NN;

  k_embed<<<NN/2, 256, 0, stream>>>(in_h, in_x, eiw, eib, h, x);

  hipMemsetAsync(cnt, 0, (size_t)NN*sizeof(float), stream);
  k_count<<<EE/256, 256, 0, stream>>>(row, cnt);

  for (int l = 0; l < LL; l++) {
    hipMemsetAsync(aggm, 0, (size_t)NN*HH*sizeof(float), stream);
    hipMemsetAsync(aggx, 0, (size_t)NN*3*sizeof(float), stream);
    k_edge<<<EE/64, 256, 0, stream>>>(h, x, row, col,
        ew1 + (size_t)l*(2*HH+1)*HH, eb1 + l*HH,
        ew2 + (size_t)l*HH*HH,       eb2 + l*HH,
        attw + l*HH, attb + l,
        cw1 + (size_t)l*HH*HH, cb1 + l*HH, cw2 + l*HH,
        aggm, aggx);
    k_node<<<(NN + 63)/64, 256, 0, stream>>>(h, x, aggm, aggx, cnt,
        nw1 + (size_t)l*(2*HH)*HH, nb1 + l*HH,
        nw2 + (size_t)l*HH*HH,     nb2 + l*HH);
  }

  hipMemsetAsync(g, 0, HH*sizeof(float), stream);
  k_pool<<<500, 128, 0, stream>>>(h, g);
  k_head<<<1, 128, 0, stream>>>(g, eow, eob, hw1, hb1, hw2, hb2, (float*)d_out);
}

// Round 3
// 3844.790 us; speedup vs baseline: 2.7710x; 2.1017x over previous
//
#include <hip/hip_runtime.h>
#include <hip/hip_bf16.h>

#define NN   50000
#define EE   800000
#define FIN  32
#define HH   128
#define LL   4
#define NOUT 20

typedef __attribute__((ext_vector_type(8))) short bf16x8;
typedef __attribute__((ext_vector_type(4))) short short4v;
typedef __attribute__((ext_vector_type(4))) float f32x4;

__device__ __forceinline__ float silu_f(float v){ return v / (1.f + __expf(-v)); }
__device__ __forceinline__ float sigm_f(float v){ return 1.f / (1.f + __expf(-v)); }

__device__ __forceinline__ short f2bf(float v){
  union { float f; unsigned u; } a; a.f = v;
  unsigned r = a.u + 0x7fff + ((a.u >> 16) & 1);
  return (short)(r >> 16);
}
__device__ __forceinline__ float bf2f(short s){
  union { unsigned u; float f; } a; a.u = ((unsigned)(unsigned short)s) << 16;
  return a.f;
}

__device__ __forceinline__ f32x4 mfma16(bf16x8 a, bf16x8 b, f32x4 c){
  return __builtin_amdgcn_mfma_f32_16x16x32_bf16(a, b, c, 0, 0, 0);
}

// ---------------------------------------------------------------------------
// A staged in LDS as bf16 hi/lo, element (e,k) at short index e*128 + (k ^ ((e&7)<<3)).
// Split-bf16 MFMA GEMM: C[64x(32/wave)] += A[64x128] @ W[128x128].
// Wave w covers cols [32w,32w+32). acc[fr][cf]: rows fr*16+(l>>4)*4+reg, col wc0+cf*16+(l&15).
// ---------------------------------------------------------------------------
__device__ __forceinline__ void gemm_mfma(const short* Ah, const short* Al,
                                          const float* __restrict__ W,
                                          int lane, int wc0, f32x4 acc[4][2])
{
  const int cl = lane & 15, g = lane >> 4;
  bf16x8 Bh[4][2], Bl[4][2];
  #pragma unroll
  for (int kb = 0; kb < 4; kb++) {
    #pragma unroll
    for (int cf = 0; cf < 2; cf++) {
      const float* wp = W + (size_t)(kb*32 + g*8)*HH + wc0 + cf*16 + cl;
      bf16x8 hv, lv;
      #pragma unroll
      for (int j = 0; j < 8; j++) {
        const float v = wp[(size_t)j*HH];
        const short hh = f2bf(v);
        const short ll = f2bf(v - bf2f(hh));
        hv[j] = hh; lv[j] = ll;
      }
      Bh[kb][cf] = hv; Bl[kb][cf] = lv;
    }
  }
  #pragma unroll
  for (int kb = 0; kb < 4; kb++) {
    #pragma unroll
    for (int fr = 0; fr < 4; fr++) {
      const int e = fr*16 + cl;
      const int off = e*128 + ((kb*32 + g*8) ^ ((e&7)<<3));
      const bf16x8 ah = *(const bf16x8*)&Ah[off];
      const bf16x8 al = *(const bf16x8*)&Al[off];
      #pragma unroll
      for (int cf = 0; cf < 2; cf++) {
        acc[fr][cf] = mfma16(ah, Bh[kb][cf], acc[fr][cf]);
        acc[fr][cf] = mfma16(ah, Bl[kb][cf], acc[fr][cf]);
        acc[fr][cf] = mfma16(al, Bh[kb][cf], acc[fr][cf]);
      }
    }
  }
}

// gather h[idx[e]] (fp32) -> Ah/Al (bf16 hi/lo, swizzled)
__device__ __forceinline__ void stage_h(const float* __restrict__ hsrc, const int* idx,
                                        short* Ah, short* Al, int tid)
{
  const int l32 = tid & 31, hgr = tid >> 5;
  const int c4 = l32 * 4;
  #pragma unroll
  for (int j = 0; j < 8; j++) {
    const int e = hgr + 8*j;
    const float4 v = *(const float4*)&hsrc[(size_t)idx[e]*HH + c4];
    short4v hv, lv;
    hv.x = f2bf(v.x); lv.x = f2bf(v.x - bf2f(hv.x));
    hv.y = f2bf(v.y); lv.y = f2bf(v.y - bf2f(hv.y));
    hv.z = f2bf(v.z); lv.z = f2bf(v.z - bf2f(hv.z));
    hv.w = f2bf(v.w); lv.w = f2bf(v.w - bf2f(hv.w));
    const int o = e*128 + (c4 ^ ((e&7)<<3));
    *(short4v*)&Ah[o] = hv;
    *(short4v*)&Al[o] = lv;
  }
}

// ---------------- input embedding + x copy ----------------
__global__ __launch_bounds__(256)
void k_embed(const float* __restrict__ hin, const float* __restrict__ xin,
             const float* __restrict__ W, const float* __restrict__ b,
             float* __restrict__ hout, float* __restrict__ xout)
{
  __shared__ float wl[FIN*HH];
  const int tid = threadIdx.x;
  for (int j = tid; j < FIN*HH; j += 256) wl[j] = W[j];
  __syncthreads();
  const int c  = tid & (HH-1);
  const int no = tid >> 7;
  const int v  = blockIdx.x * 2 + no;
  if (v < NN) {
    const float* hr = hin + (size_t)v * FIN;
    float acc = b[c];
    #pragma unroll
    for (int k = 0; k < FIN; k++) acc = fmaf(hr[k], wl[k*HH + c], acc);
    hout[(size_t)v*HH + c] = acc;
    if (c < 3) xout[v*3 + c] = xin[v*3 + c];
  }
}

// ---------------- degree count ----------------
__global__ __launch_bounds__(256)
void k_count(const int* __restrict__ row, int* __restrict__ deg)
{
  const int e = blockIdx.x * 256 + threadIdx.x;
  if (e < EE) atomicAdd(&deg[row[e]], 1);
}

// ---------------- single-block exclusive prefix scan over deg ----------------
__global__ __launch_bounds__(1024)
void k_scan(const int* __restrict__ deg, int* __restrict__ offs, int* __restrict__ cursor)
{
  __shared__ int part[1024];
  const int t = threadIdx.x;
  const int base = t * 49;                    // 1024*49 = 50176 >= NN
  int s = 0;
  for (int i = 0; i < 49; i++) { const int idx = base + i; s += (idx < NN) ? deg[idx] : 0; }
  part[t] = s;
  __syncthreads();
  if (t == 0) { int run = 0; for (int i = 0; i < 1024; i++) { const int v = part[i]; part[i] = run; run += v; } }
  __syncthreads();
  int run = part[t];
  for (int i = 0; i < 49; i++) {
    const int idx = base + i;
    if (idx < NN) { offs[idx] = run; cursor[idx] = run; run += deg[idx]; }
  }
  if (t == 1023) offs[NN] = EE;
}

// ---------------- per-edge slot assignment ----------------
__global__ __launch_bounds__(256)
void k_pos(const int* __restrict__ row, int* __restrict__ cursor, int* __restrict__ pos)
{
  const int e = blockIdx.x * 256 + threadIdx.x;
  if (e < EE) pos[e] = atomicAdd(&cursor[row[e]], 1);
}

// ---------------- fused edge pipeline (split-bf16 MFMA) ----------------
template<bool SC>
__global__ __launch_bounds__(256)
void k_edge(const float* __restrict__ hbuf, const float* __restrict__ xbuf,
            const int* __restrict__ row, const int* __restrict__ col,
            const int* __restrict__ pos,
            const float* __restrict__ W1, const float* __restrict__ b1,
            const float* __restrict__ W2, const float* __restrict__ b2,
            const float* __restrict__ attw, const float* __restrict__ attb,
            const float* __restrict__ cw1, const float* __restrict__ cb1,
            const float* __restrict__ cw2,
            float* __restrict__ mbuf, float* __restrict__ aggx)
{
  __shared__ short Ah[64*128];
  __shared__ short Al[64*128];
  __shared__ float red[4][64];
  __shared__ float scal[64];
  __shared__ int   rowb[64];
  __shared__ int   colb[64];
  __shared__ int   posb[64];
  __shared__ float diffb[64][3];
  __shared__ float radb[64];

  const int tid  = threadIdx.x;
  const int lane = tid & 63;
  const int wv   = tid >> 6;
  const int cl   = lane & 15;
  const int g    = lane >> 4;
  const int wc0  = wv * 32;
  const int col0 = wc0 + cl;
  const int col1 = wc0 + 16 + cl;
  const int eb   = blockIdx.x * 64;

  if (tid < 64) {
    const int r  = row[eb + tid];
    const int c2 = col[eb + tid];
    rowb[tid] = r; colb[tid] = c2;
    if (SC) posb[tid] = pos[eb + tid];
    const float dx = xbuf[r*3+0] - xbuf[c2*3+0];
    const float dy = xbuf[r*3+1] - xbuf[c2*3+1];
    const float dz = xbuf[r*3+2] - xbuf[c2*3+2];
    diffb[tid][0] = dx; diffb[tid][1] = dy; diffb[tid][2] = dz;
    radb[tid] = dx*dx + dy*dy + dz*dz;
  }
  __syncthreads();                     // 1

  // ---- GEMM1: [h_row | h_col | radial] @ W1 ----
  stage_h(hbuf, rowb, Ah, Al, tid);
  __syncthreads();                     // 2

  f32x4 acc[4][2];
  #pragma unroll
  for (int fr = 0; fr < 4; fr++) { acc[fr][0] = (f32x4){0,0,0,0}; acc[fr][1] = (f32x4){0,0,0,0}; }
  gemm_mfma(Ah, Al, W1, lane, wc0, acc);
  __syncthreads();                     // 3

  stage_h(hbuf, colb, Ah, Al, tid);
  __syncthreads();                     // 4

  gemm_mfma(Ah, Al, W1 + HH*HH, lane, wc0, acc);

  // radial + bias + silu (register epilogue)
  {
    const float w256a = W1[(size_t)(2*HH)*HH + col0];
    const float w256b = W1[(size_t)(2*HH)*HH + col1];
    const float bba = b1[col0], bbb = b1[col1];
    #pragma unroll
    for (int fr = 0; fr < 4; fr++) {
      #pragma unroll
      for (int j = 0; j < 4; j++) {
        const int r = fr*16 + g*4 + j;
        const float rr = radb[r];
        acc[fr][0][j] = silu_f(fmaf(rr, w256a, acc[fr][0][j]) + bba);
        acc[fr][1][j] = silu_f(fmaf(rr, w256b, acc[fr][1][j]) + bbb);
      }
    }
  }
  __syncthreads();                     // 5 (all GEMM1 reads of Ah/Al done)

  // store m1 -> Ah/Al
  #pragma unroll
  for (int fr = 0; fr < 4; fr++) {
    #pragma unroll
    for (int j = 0; j < 4; j++) {
      const int r = fr*16 + g*4 + j;
      const int sw = (r&7)<<3;
      const float v0 = acc[fr][0][j], v1 = acc[fr][1][j];
      const short h0 = f2bf(v0), h1 = f2bf(v1);
      Ah[r*128 + (col0 ^ sw)] = h0;  Al[r*128 + (col0 ^ sw)] = f2bf(v0 - bf2f(h0));
      Ah[r*128 + (col1 ^ sw)] = h1;  Al[r*128 + (col1 ^ sw)] = f2bf(v1 - bf2f(h1));
    }
  }
  __syncthreads();                     // 6

  // ---- GEMM2: m1 @ W2, bias, silu -> m2 ----
  f32x4 m2[4][2];
  #pragma unroll
  for (int fr = 0; fr < 4; fr++) { m2[fr][0] = (f32x4){0,0,0,0}; m2[fr][1] = (f32x4){0,0,0,0}; }
  gemm_mfma(Ah, Al, W2, lane, wc0, m2);
  {
    const float bba = b2[col0], bbb = b2[col1];
    #pragma unroll
    for (int fr = 0; fr < 4; fr++) {
      #pragma unroll
      for (int j = 0; j < 4; j++) {
        m2[fr][0][j] = silu_f(m2[fr][0][j] + bba);
        m2[fr][1][j] = silu_f(m2[fr][1][j] + bbb);
      }
    }
  }

  // ---- attention gate partial dot ----
  {
    const float awa = attw[col0], awb = attw[col1];
    #pragma unroll
    for (int fr = 0; fr < 4; fr++) {
      #pragma unroll
      for (int j = 0; j < 4; j++) {
        float p = fmaf(m2[fr][0][j], awa, m2[fr][1][j]*awb);
        p += __shfl_xor(p, 1); p += __shfl_xor(p, 2);
        p += __shfl_xor(p, 4); p += __shfl_xor(p, 8);
        if (cl == 0) red[wv][fr*16 + g*4 + j] = p;
      }
    }
  }
  __syncthreads();                     // 7
  if (tid < 64)
    scal[tid] = sigm_f(red[0][tid] + red[1][tid] + red[2][tid] + red[3][tid] + attb[0]);
  __syncthreads();                     // 8

  // ---- gate, scatter m, store m -> Ah/Al for coord GEMM ----
  #pragma unroll
  for (int fr = 0; fr < 4; fr++) {
    #pragma unroll
    for (int j = 0; j < 4; j++) {
      const int r = fr*16 + g*4 + j;
      const float sc = scal[r];
      const float v0 = m2[fr][0][j]*sc, v1 = m2[fr][1][j]*sc;
      m2[fr][0][j] = v0; m2[fr][1][j] = v1;
      if (SC) {
        float* dst = &mbuf[(size_t)posb[r]*HH];
        dst[col0] = v0; dst[col1] = v1;
      } else {
        float* dst = &mbuf[(size_t)rowb[r]*HH];
        atomicAdd(&dst[col0], v0); atomicAdd(&dst[col1], v1);
      }
      const int sw = (r&7)<<3;
      const short h0 = f2bf(v0), h1 = f2bf(v1);
      Ah[r*128 + (col0 ^ sw)] = h0;  Al[r*128 + (col0 ^ sw)] = f2bf(v0 - bf2f(h0));
      Ah[r*128 + (col1 ^ sw)] = h1;  Al[r*128 + (col1 ^ sw)] = f2bf(v1 - bf2f(h1));
    }
  }
  __syncthreads();                     // 9

  // ---- GEMM3: coord layer1 (silu), dot with cw2 ----
  f32x4 a3[4][2];
  #pragma unroll
  for (int fr = 0; fr < 4; fr++) { a3[fr][0] = (f32x4){0,0,0,0}; a3[fr][1] = (f32x4){0,0,0,0}; }
  gemm_mfma(Ah, Al, cw1, lane, wc0, a3);
  {
    const float bba = cb1[col0], bbb = cb1[col1];
    const float c2a = cw2[col0], c2b = cw2[col1];
    #pragma unroll
    for (int fr = 0; fr < 4; fr++) {
      #pragma unroll
      for (int j = 0; j < 4; j++) {
        float p = fmaf(silu_f(a3[fr][0][j] + bba), c2a, silu_f(a3[fr][1][j] + bbb)*c2b);
        p += __shfl_xor(p, 1); p += __shfl_xor(p, 2);
        p += __shfl_xor(p, 4); p += __shfl_xor(p, 8);
        if (cl == 0) red[wv][fr*16 + g*4 + j] = p;
      }
    }
  }
  __syncthreads();                     // 10

  if (tid < 64) {
    const float cwv = red[0][tid] + red[1][tid] + red[2][tid] + red[3][tid];
    const int r = rowb[tid];
    atomicAdd(&aggx[r*3+0], diffb[tid][0]*cwv);
    atomicAdd(&aggx[r*3+1], diffb[tid][1]*cwv);
    atomicAdd(&aggx[r*3+2], diffb[tid][2]*cwv);
  }
}

// ---------------- fused node update ----------------
__device__ __forceinline__ void gemm_accum(const float (*buf)[132], const float* __restrict__ W,
                                           int c, int eo, float acc[32])
{
  for (int k0 = 0; k0 < HH; k0 += 4) {
    const float w0 = W[(k0+0)*HH + c];
    const float w1 = W[(k0+1)*HH + c];
    const float w2 = W[(k0+2)*HH + c];
    const float w3 = W[(k0+3)*HH + c];
    #pragma unroll
    for (int i = 0; i < 32; i++) {
      const float4 a = *(const float4*)&buf[eo*32+i][k0];
      acc[i] = fmaf(a.x, w0, fmaf(a.y, w1, fmaf(a.z, w2, fmaf(a.w, w3, acc[i]))));
    }
  }
}

template<bool SC>
__global__ __launch_bounds__(256, 2)
void k_node(float* __restrict__ hbuf, float* __restrict__ xbuf,
            const float* __restrict__ mbuf, const int* __restrict__ offs,
            const float* __restrict__ aggx,
            const float* __restrict__ W1, const float* __restrict__ b1,
            const float* __restrict__ W2, const float* __restrict__ b2)
{
  __shared__ float bufA[64][132];
  __shared__ float bufB[64][132];
  const int tid = threadIdx.x;
  const int c   = tid & (HH-1);
  const int no  = tid >> 7;
  const int nb  = blockIdx.x * 64;

  #pragma unroll
  for (int i = 0; i < 32; i++) {
    const int v = nb + no*32 + i;
    bufA[no*32+i][c] = (v < NN) ? hbuf[(size_t)v*HH + c] : 0.f;
  }
  __syncthreads();

  float acc[32];
  #pragma unroll
  for (int i = 0; i < 32; i++) acc[i] = 0.f;
  gemm_accum(bufA, W1, c, no, acc);
  __syncthreads();

  for (int i = 0; i < 32; i++) {
    const int v = nb + no*32 + i;
    float s = 0.f;
    if (v < NN) {
      if (SC) {
        const int beg = offs[v], end = offs[v+1];
        for (int j = beg; j < end; j++) s += mbuf[(size_t)j*HH + c];
      } else {
        s = mbuf[(size_t)v*HH + c];
      }
    }
    bufA[no*32+i][c] = s;
  }
  __syncthreads();
  gemm_accum(bufA, W1 + HH*HH, c, no, acc);
  {
    const float bb = b1[c];
    #pragma unroll
    for (int i = 0; i < 32; i++) bufB[no*32+i][c] = silu_f(acc[i] + bb);
  }
  __syncthreads();

  #pragma unroll
  for (int i = 0; i < 32; i++) acc[i] = 0.f;
  gemm_accum(bufB, W2, c, no, acc);
  {
    const float bb = b2[c];
    #pragma unroll
    for (int i = 0; i < 32; i++) {
      const int v = nb + no*32 + i;
      if (v < NN) hbuf[(size_t)v*HH + c] += acc[i] + bb;
    }
  }

  if (tid < 64) {
    const int v = nb + tid;
    if (v < NN) {
      const float ct = fmaxf((float)(offs[v+1] - offs[v]), 1.f);
      xbuf[v*3+0] += aggx[v*3+0] / ct;
      xbuf[v*3+1] += aggx[v*3+1] / ct;
      xbuf[v*3+2] += aggx[v*3+2] / ct;
    }
  }
}

// ---------------- mean pool ----------------
__global__ __launch_bounds__(128)
void k_pool(const float* __restrict__ h, float* __restrict__ g)
{
  const int c  = threadIdx.x;
  const int v0 = blockIdx.x * 100;
  float s = 0.f;
  for (int v = v0; v < v0 + 100; ++v) s += h[(size_t)v*HH + c];
  atomicAdd(&g[c], s);
}

// ---------------- out-embed (folded through mean) + head MLP ----------------
__global__ __launch_bounds__(128)
void k_head(const float* __restrict__ g,
            const float* __restrict__ eow, const float* __restrict__ eob,
            const float* __restrict__ hw1, const float* __restrict__ hb1,
            const float* __restrict__ hw2, const float* __restrict__ hb2,
            float* __restrict__ out)
{
  __shared__ float gm[HH], ho[HH], t1[HH];
  const int c = threadIdx.x;
  gm[c] = g[c] * (1.f / (float)NN);
  __syncthreads();
  float a = eob[c];
  for (int k = 0; k < HH; k++) a = fmaf(gm[k], eow[k*HH + c], a);
  ho[c] = a;
  __syncthreads();
  float t = hb1[c];
  for (int k = 0; k < HH; k++) t = fmaf(ho[k], hw1[k*HH + c], t);
  t1[c] = fmaxf(t, 0.f);
  __syncthreads();
  if (c < NOUT) {
    float o = hb2[c];
    for (int k = 0; k < HH; k++) o = fmaf(t1[k], hw2[k*NOUT + c], o);
    out[c] = o;
  }
}

extern "C" void kernel_launch(void* const* d_in, const int* in_sizes, int n_in,
                              void* d_out, int out_size, void* d_ws, size_t ws_size,
                              hipStream_t stream)
{
  const float* in_h  = (const float*)d_in[0];
  const float* in_x  = (const float*)d_in[1];
  const int*   edges = (const int*)  d_in[2];
  const float* eiw   = (const float*)d_in[3];
  const float* eib   = (const float*)d_in[4];
  const float* eow   = (const float*)d_in[5];
  const float* eob   = (const float*)d_in[6];
  const float* ew1   = (const float*)d_in[7];
  const float* eb1   = (const float*)d_in[8];
  const float* ew2   = (const float*)d_in[9];
  const float* eb2   = (const float*)d_in[10];
  const float* attw  = (const float*)d_in[11];
  const float* attb  = (const float*)d_in[12];
  const float* cw1   = (const float*)d_in[13];
  const float* cb1   = (const float*)d_in[14];
  const float* cw2   = (const float*)d_in[15];
  const float* nw1   = (const float*)d_in[16];
  const float* nb1   = (const float*)d_in[17];
  const float* nw2   = (const float*)d_in[18];
  const float* nb2   = (const float*)d_in[19];
  const float* hw1   = (const float*)d_in[20];
  const float* hb1   = (const float*)d_in[21];
  const float* hw2   = (const float*)d_in[22];
  const float* hb2   = (const float*)d_in[23];

  const int* row = edges;
  const int* col = edges + EE;

  // workspace layout (256B aligned slots)
  char* p = (char*)d_ws;
  auto alloc = [&](size_t bytes) { char* r = p; p += (bytes + 255) & ~(size_t)255; return r; };
  float* h    = (float*)alloc((size_t)NN*HH*4);
  float* x    = (float*)alloc((size_t)NN*3*4);
  float* aggx = (float*)alloc((size_t)NN*3*4);
  float* g    = (float*)alloc(HH*4);
  int*   deg  = (int*)  alloc((size_t)NN*4);
  int*   offs = (int*)  alloc((size_t)(NN+1)*4);
  int*   curs = (int*)  alloc((size_t)NN*4);
  int*   pos  = (int*)  alloc((size_t)EE*4);
  const size_t baseUsed = (size_t)(p - (char*)d_ws);
  const bool sc = (ws_size >= baseUsed + (size_t)EE*HH*4);
  float* mbuf = (float*)alloc(sc ? (size_t)EE*HH*4 : (size_t)NN*HH*4);  // mbuf or aggm

  k_embed<<<NN/2, 256, 0, stream>>>(in_h, in_x, eiw, eib, h, x);

  hipMemsetAsync(deg, 0, (size_t)NN*4, stream);
  k_count<<<(EE+255)/256, 256, 0, stream>>>(row, deg);
  k_scan<<<1, 1024, 0, stream>>>(deg, offs, curs);
  k_pos<<<(EE+255)/256, 256, 0, stream>>>(row, curs, pos);

  for (int l = 0; l < LL; l++) {
    hipMemsetAsync(aggx, 0, (size_t)NN*3*4, stream);
    if (!sc) hipMemsetAsync(mbuf, 0, (size_t)NN*HH*4, stream);
    if (sc) {
      k_edge<true><<<EE/64, 256, 0, stream>>>(h, x, row, col, pos,
          ew1 + (size_t)l*(2*HH+1)*HH, eb1 + l*HH,
          ew2 + (size_t)l*HH*HH,       eb2 + l*HH,
          attw + l*HH, attb + l,
          cw1 + (size_t)l*HH*HH, cb1 + l*HH, cw2 + l*HH,
          mbuf, aggx);
      k_node<true><<<(NN + 63)/64, 256, 0, stream>>>(h, x, mbuf, offs, aggx,
          nw1 + (size_t)l*(2*HH)*HH, nb1 + l*HH,
          nw2 + (size_t)l*HH*HH,     nb2 + l*HH);
    } else {
      k_edge<false><<<EE/64, 256, 0, stream>>>(h, x, row, col, pos,
          ew1 + (size_t)l*(2*HH+1)*HH, eb1 + l*HH,
          ew2 + (size_t)l*HH*HH,       eb2 + l*HH,
          attw + l*HH, attb + l,
          cw1 + (size_t)l*HH*HH, cb1 + l*HH, cw2 + l*HH,
          mbuf, aggx);
      k_node<false><<<(NN + 63)/64, 256, 0, stream>>>(h, x, mbuf, offs, aggx,
          nw1 + (size_t)l*(2*HH)*HH, nb1 + l*HH,
          nw2 + (size_t)l*HH*HH,     nb2 + l*HH);
    }
  }

  hipMemsetAsync(g, 0, HH*4, stream);
  k_pool<<<500, 128, 0, stream>>>(h, g);
  k_head<<<1, 128, 0, stream>>>(g, eow, eob, hw1, hb1, hw2, hb2, (float*)d_out);
}